// Round 3
// baseline (595.919 us; speedup 1.0000x reference)
//
#include <hip/hip_runtime.h>
#include <hip/hip_bf16.h>
#include <stdint.h>

#define SS 1024
#define DD 128
#define TQ 128          // q rows per block
#define TK 64           // kv cols per tile
#define NKT (SS/TK)     // 16
#define THREADS 256     // 4 waves
#define NHEAD 128

typedef short bf16x8 __attribute__((ext_vector_type(8)));
typedef float f32x4  __attribute__((ext_vector_type(4)));

// ---------------- threefry2x32, key = (0, 42) — verified bit-exact (R1) ----
__device__ __forceinline__ uint32_t rotl32(uint32_t v, uint32_t s) {
  return (v << s) | (v >> (32u - s));
}
__device__ __forceinline__ uint32_t threefry_bits(uint32_t ctr) {
  const uint32_t K0 = 0u, K1 = 42u;
  const uint32_t K2 = K0 ^ K1 ^ 0x1BD11BDAu;
  uint32_t x0 = K0;
  uint32_t x1 = ctr + K1;
#define TF_RND(r) { x0 += x1; x1 = rotl32(x1, r); x1 ^= x0; }
  TF_RND(13u) TF_RND(15u) TF_RND(26u) TF_RND(6u)
  x0 += K1; x1 += K2 + 1u;
  TF_RND(17u) TF_RND(29u) TF_RND(16u) TF_RND(24u)
  x0 += K2; x1 += K0 + 2u;
  TF_RND(13u) TF_RND(15u) TF_RND(26u) TF_RND(6u)
  x0 += K0; x1 += K1 + 3u;
  TF_RND(17u) TF_RND(29u) TF_RND(16u) TF_RND(24u)
  x0 += K1; x1 += K2 + 4u;
  TF_RND(13u) TF_RND(15u) TF_RND(26u) TF_RND(6u)
  x0 += K2; x1 += K0 + 5u;
#undef TF_RND
  return x0 ^ x1;
}

// keep-bit word: bit b set iff uniform(threefry(base+b)) < 0.9
__device__ __forceinline__ uint32_t maskword(uint32_t base) {
  uint32_t w = 0u;
#pragma unroll 4
  for (int b = 0; b < 32; ++b) {
    uint32_t bits = threefry_bits(base + (uint32_t)b);
    w |= (bits < 0xE6666600u) ? (1u << b) : 0u;
  }
  return w;
}

// ---------------- bf16 helpers --------------------------------------------
__device__ __forceinline__ short f2bf(float x) {
  return __builtin_bit_cast(short, __float2bfloat16(x));   // RNE
}
__device__ __forceinline__ float bf2f(short b) {
  return __uint_as_float(((uint32_t)(uint16_t)b) << 16);
}
__device__ __forceinline__ uint32_t pack2(short a, short b) {
  return (uint32_t)(uint16_t)a | ((uint32_t)(uint16_t)b << 16);
}
__device__ __forceinline__ void split2(float x, short& hi, short& lo) {
  hi = f2bf(x);
  lo = f2bf(x - bf2f(hi));
}

#define MFMA16(A, B, C) __builtin_amdgcn_mfma_f32_16x16x32_bf16(A, B, C, 0, 0, 0)

// LDS layout (shorts), 16B-aligned base:
//  phase 1: Qhi[128][136] @0, Qlo[128][136] @17408 (ends 34816)
//  phase 2: Khi[64][136] @0, Klo[64][136] @8704,
//           Vt[128][72] @17408 (k-permuted), Pt[128][72] @26624 (k-permuted),
//           Ms[256 u32]  @35840 (mask words for current kt)
#define SMEM_SHORTS 36352

__global__ __launch_bounds__(THREADS, 2) void pm_attn(
    const float* __restrict__ Qg, const float* __restrict__ Kg,
    const float* __restrict__ Vg, const float* __restrict__ isf,
    float* __restrict__ Og)
{
  __shared__ __align__(16) short smem[SMEM_SHORTS];
  short* const Qhi = smem;
  short* const Qlo = smem + 17408;
  short* const Khi = smem;
  short* const Klo = smem + 8704;
  short* const Vt  = smem + 17408;
  short* const Pt  = smem + 26624;
  uint32_t* const Ms = (uint32_t*)(smem + 35840);

  const int tid  = threadIdx.x;
  const int lane = tid & 63;
  const int wid  = tid >> 6;       // wave 0..3, owns q rows [wid*32, wid*32+32)
  const int lg   = lane >> 4;      // 16-lane group 0..3
  const int tx   = lane & 15;

  // XCD-aware swizzle: same-head blocks colocate on one XCD (1024 % 8 == 0)
  const int swz   = (blockIdx.x & 7) * 128 + (blockIdx.x >> 3);
  const int head  = swz >> 3;
  const int qbase = (swz & 7) * TQ;

  const size_t hoff = (size_t)head * (SS * DD);
  const float* Qh = Qg + hoff + (size_t)qbase * DD;
  const float* Kh = Kg + hoff;
  const float* Vh = Vg + hoff;
  float*       Oh = Og + hoff + (size_t)qbase * DD;

  // threefry counter base for this thread's mask word:
  // word (lrow = tid>>1, half = tid&1); element flat idx = (head*1024+q)*1024 + k
  const uint32_t ctr0 = (((uint32_t)head << 20) |
                         ((uint32_t)(qbase + (tid >> 1)) << 10)) |
                        ((uint32_t)(tid & 1) << 5);

  // ---- phase 1: stage Q (fp32 -> hi/lo bf16 in LDS), then frags -> VGPRs ----
#pragma unroll
  for (int i = 0; i < 16; ++i) {
    int f = tid * 4 + i * 1024;
    float4 q4 = *(const float4*)(Qh + f);
    int row = f >> 7, col = f & 127;
    short h0, h1, h2, h3, l0, l1, l2, l3;
    split2(q4.x, h0, l0); split2(q4.y, h1, l1);
    split2(q4.z, h2, l2); split2(q4.w, h3, l3);
    uint2 ph = { pack2(h0, h1), pack2(h2, h3) };
    uint2 pl = { pack2(l0, l1), pack2(l2, l3) };
    *(uint2*)&Qhi[row * 136 + col] = ph;
    *(uint2*)&Qlo[row * 136 + col] = pl;
  }
  __syncthreads();

  bf16x8 qhi[2][4], qlo[2][4];
#pragma unroll
  for (int qi = 0; qi < 2; ++qi)
#pragma unroll
    for (int ds = 0; ds < 4; ++ds) {
      int off = (wid * 32 + qi * 16 + tx) * 136 + ds * 32 + lg * 8;
      qhi[qi][ds] = *(const bf16x8*)&Qhi[off];
      qlo[qi][ds] = *(const bf16x8*)&Qlo[off];
    }
  // barrier (a) of kt=0 protects the Q->K LDS region reuse

  f32x4 acc[2][8];
  float mrun[2][4], lrun[2][4];
#pragma unroll
  for (int qi = 0; qi < 2; ++qi)
#pragma unroll
    for (int r = 0; r < 4; ++r) {
      mrun[qi][r] = -1e30f;
      lrun[qi][r] = 0.f;
    }
#pragma unroll
  for (int qi = 0; qi < 2; ++qi)
#pragma unroll
    for (int n = 0; n < 8; ++n)
      acc[qi][n] = (f32x4){0.f, 0.f, 0.f, 0.f};

  // prologue: mask word for kt = 0
  uint32_t myw = maskword(ctr0);

  const int vd  = tid & 127;        // V-stage: this thread's d row
  const int vt8 = (tid >> 7) * 8;   // and its 8 tx values (k' = tx*4+kj)

  for (int kt = 0; kt < NKT; ++kt) {
    const float* Kt  = Kh + (size_t)kt * (TK * DD);
    const float* Vtg = Vh + (size_t)kt * (TK * DD);

    __syncthreads();   // (a): prev PV done reading LDS / Q-frag reads done

    // commit this tile's mask words
    Ms[tid] = myw;

    // ---- stage K tile: fp32 -> hi/lo bf16 ----
#pragma unroll
    for (int i = 0; i < 8; ++i) {
      int f = tid * 4 + i * 1024;
      float4 k4 = *(const float4*)(Kt + f);
      int row = f >> 7, col = f & 127;
      short h0, h1, h2, h3, l0, l1, l2, l3;
      split2(k4.x, h0, l0); split2(k4.y, h1, l1);
      split2(k4.z, h2, l2); split2(k4.w, h3, l3);
      uint2 ph = { pack2(h0, h1), pack2(h2, h3) };
      uint2 pl = { pack2(l0, l1), pack2(l2, l3) };
      *(uint2*)&Khi[row * 136 + col] = ph;
      *(uint2*)&Klo[row * 136 + col] = pl;
    }
    // ---- stage V tile, k-permuted transpose: Vt[d][k'=tx*4+kj] = V[kj*16+tx][d]
#pragma unroll
    for (int t8 = 0; t8 < 8; ++t8) {
      int txv = vt8 + t8;
      float a0 = Vtg[(0 * 16 + txv) * DD + vd];
      float a1 = Vtg[(1 * 16 + txv) * DD + vd];
      float a2 = Vtg[(2 * 16 + txv) * DD + vd];
      float a3 = Vtg[(3 * 16 + txv) * DD + vd];
      uint2 w = { pack2(f2bf(a0), f2bf(a1)), pack2(f2bf(a2), f2bf(a3)) };
      *(uint2*)&Vt[vd * 72 + txv * 4] = w;
    }
    __syncthreads();   // (b): K/V/mask visible

    // ---- QK^T: hi*hi + lo*hi + hi*lo (bf16x2 split) ----
    f32x4 sc[2][4];
#pragma unroll
    for (int qi = 0; qi < 2; ++qi)
#pragma unroll
      for (int kj = 0; kj < 4; ++kj)
        sc[qi][kj] = (f32x4){0.f, 0.f, 0.f, 0.f};

#pragma unroll
    for (int ds = 0; ds < 4; ++ds) {
#pragma unroll
      for (int kj = 0; kj < 4; ++kj) {
        int off = (kj * 16 + tx) * 136 + ds * 32 + lg * 8;
        bf16x8 bhi = *(const bf16x8*)&Khi[off];
        bf16x8 blo = *(const bf16x8*)&Klo[off];
#pragma unroll
        for (int qi = 0; qi < 2; ++qi) {
          sc[qi][kj] = MFMA16(qhi[qi][ds], bhi, sc[qi][kj]);
          sc[qi][kj] = MFMA16(qlo[qi][ds], bhi, sc[qi][kj]);
          sc[qi][kj] = MFMA16(qhi[qi][ds], blo, sc[qi][kj]);
        }
      }
    }

    // ---- column scale 1/isf, online softmax, dropout, packed P write ----
    float rs[4];
#pragma unroll
    for (int kj = 0; kj < 4; ++kj)
      rs[kj] = __builtin_amdgcn_rcpf(isf[kt * 64 + kj * 16 + tx]);

#pragma unroll
    for (int qi = 0; qi < 2; ++qi) {
#pragma unroll
      for (int r = 0; r < 4; ++r) {
        float s0 = sc[qi][0][r] * rs[0];
        float s1 = sc[qi][1][r] * rs[1];
        float s2 = sc[qi][2][r] * rs[2];
        float s3 = sc[qi][3][r] * rs[3];
        float mt = fmaxf(fmaxf(s0, s1), fmaxf(s2, s3));
        mt = fmaxf(mt, __shfl_xor(mt, 1, 64));
        mt = fmaxf(mt, __shfl_xor(mt, 2, 64));
        mt = fmaxf(mt, __shfl_xor(mt, 4, 64));
        mt = fmaxf(mt, __shfl_xor(mt, 8, 64));
        float mold = mrun[qi][r];
        float mnew = fmaxf(mold, mt);
        float corr = __expf(mold - mnew);
        mrun[qi][r] = mnew;
        float e0 = __expf(s0 - mnew);
        float e1 = __expf(s1 - mnew);
        float e2 = __expf(s2 - mnew);
        float e3 = __expf(s3 - mnew);
        float rsum = (e0 + e1) + (e2 + e3);
        rsum += __shfl_xor(rsum, 1, 64);
        rsum += __shfl_xor(rsum, 2, 64);
        rsum += __shfl_xor(rsum, 4, 64);
        rsum += __shfl_xor(rsum, 8, 64);
        lrun[qi][r] = lrun[qi][r] * corr + rsum;
#pragma unroll
        for (int n = 0; n < 8; ++n) acc[qi][n][r] *= corr;

        int lrow = wid * 32 + qi * 16 + lg * 4 + r;       // block-local q row
        uint2 ww = *(const uint2*)&Ms[lrow * 2];
        short p0 = ((ww.x >> tx) & 1u)        ? f2bf(e0) : (short)0;
        short p1 = ((ww.x >> (tx + 16)) & 1u) ? f2bf(e1) : (short)0;
        short p2 = ((ww.y >> tx) & 1u)        ? f2bf(e2) : (short)0;
        short p3 = ((ww.y >> (tx + 16)) & 1u) ? f2bf(e3) : (short)0;
        uint2 pw = { pack2(p0, p1), pack2(p2, p3) };
        *(uint2*)&Pt[lrow * 72 + tx * 4] = pw;   // k' = tx*4 + kj
      }
    }

    // software-pipelined mask word for next tile (overlaps MFMA/VALU phases)
    if (kt + 1 < NKT) myw = maskword(ctr0 + (uint32_t)((kt + 1) * 64));

    __syncthreads();   // (c): P ready

    // ---- PV: acc[q][d] += P[q][k'] * Vt[d][k'] (k-permuted, consistent) ----
#pragma unroll
    for (int ks = 0; ks < 2; ++ks) {
      bf16x8 pa0 = *(const bf16x8*)&Pt[(wid * 32 + tx) * 72 + ks * 32 + lg * 8];
      bf16x8 pa1 = *(const bf16x8*)&Pt[(wid * 32 + 16 + tx) * 72 + ks * 32 + lg * 8];
#pragma unroll
      for (int n = 0; n < 8; ++n) {
        bf16x8 vb = *(const bf16x8*)&Vt[(n * 16 + tx) * 72 + ks * 32 + lg * 8];
        acc[0][n] = MFMA16(pa0, vb, acc[0][n]);
        acc[1][n] = MFMA16(pa1, vb, acc[1][n]);
      }
    }
  }

  // ---- epilogue: out = acc / (0.9 * l) ----
#pragma unroll
  for (int qi = 0; qi < 2; ++qi)
#pragma unroll
    for (int r = 0; r < 4; ++r) {
      float inv = 1.0f / (0.9f * lrun[qi][r]);
      int qrow = wid * 32 + qi * 16 + lg * 4 + r;
#pragma unroll
      for (int n = 0; n < 8; ++n)
        Oh[qrow * DD + n * 16 + tx] = acc[qi][n][r] * inv;
    }
}

extern "C" void kernel_launch(void* const* d_in, const int* in_sizes, int n_in,
                              void* d_out, int out_size, void* d_ws, size_t ws_size,
                              hipStream_t stream) {
  const float* q   = (const float*)d_in[0];
  const float* k   = (const float*)d_in[1];
  const float* v   = (const float*)d_in[2];
  const float* isf = (const float*)d_in[3];

  pm_attn<<<dim3(NHEAD * (SS / TQ)), dim3(THREADS), 0, stream>>>(
      q, k, v, isf, (float*)d_out);
}

// Round 4
// 487.384 us; speedup vs baseline: 1.2227x; 1.2227x over previous
//
#include <hip/hip_runtime.h>
#include <hip/hip_bf16.h>
#include <stdint.h>

#define SS 1024
#define DD 128
#define TQ 128          // q rows per block
#define TK 64           // kv cols per tile
#define NKT (SS/TK)     // 16
#define THREADS 512     // 8 waves
#define NHEAD 128
#define LOG2E 1.44269504088896340736f
#define DEFER_THR 11.5415603f   // 8 * log2e

typedef short bf16x8 __attribute__((ext_vector_type(8)));
typedef float f32x4  __attribute__((ext_vector_type(4)));

// ---------------- threefry2x32, key = (0, 42) — bit-exact (R1) -------------
__device__ __forceinline__ uint32_t rotl32(uint32_t v, uint32_t s) {
#if __has_builtin(__builtin_rotateleft32)
  return __builtin_rotateleft32(v, s);   // v_alignbit_b32
#else
  return (v << s) | (v >> (32u - s));
#endif
}
__device__ __forceinline__ uint32_t threefry_bits(uint32_t ctr) {
  const uint32_t K0 = 0u, K1 = 42u;
  const uint32_t K2 = K0 ^ K1 ^ 0x1BD11BDAu;
  uint32_t x0 = K0;
  uint32_t x1 = ctr + K1;
#define TF_RND(r) { x0 += x1; x1 = rotl32(x1, r); x1 ^= x0; }
  TF_RND(13u) TF_RND(15u) TF_RND(26u) TF_RND(6u)
  x0 += K1; x1 += K2 + 1u;
  TF_RND(17u) TF_RND(29u) TF_RND(16u) TF_RND(24u)
  x0 += K2; x1 += K0 + 2u;
  TF_RND(13u) TF_RND(15u) TF_RND(26u) TF_RND(6u)
  x0 += K0; x1 += K1 + 3u;
  TF_RND(17u) TF_RND(29u) TF_RND(16u) TF_RND(24u)
  x0 += K1; x1 += K2 + 4u;
  TF_RND(13u) TF_RND(15u) TF_RND(26u) TF_RND(6u)
  x0 += K2; x1 += K0 + 5u;
#undef TF_RND
  return x0 ^ x1;
}
// 16 keep-bits starting at element counter `base` (bit b: uniform < 0.9f)
__device__ __forceinline__ uint32_t maskhalf(uint32_t base) {
  uint32_t h = 0u;
#pragma unroll 4
  for (int b = 0; b < 16; ++b)
    h |= (threefry_bits(base + (uint32_t)b) < 0xE6666600u) ? (1u << b) : 0u;
  return h;
}

// ---------------- bf16 helpers --------------------------------------------
__device__ __forceinline__ short f2bf(float x) {
  return __builtin_bit_cast(short, __float2bfloat16(x));   // RNE
}
__device__ __forceinline__ float bf2f(short b) {
  return __uint_as_float(((uint32_t)(uint16_t)b) << 16);
}
__device__ __forceinline__ uint32_t pack2(short a, short b) {
  return (uint32_t)(uint16_t)a | ((uint32_t)(uint16_t)b << 16);
}
__device__ __forceinline__ void split2(float x, short& hi, short& lo) {
  hi = f2bf(x);
  lo = f2bf(x - bf2f(hi));
}

#define MFMA16(A, B, C) __builtin_amdgcn_mfma_f32_16x16x32_bf16(A, B, C, 0, 0, 0)

// LDS layout (shorts):
//  Khi[64][136] @0, Klo[64][136] @8704,
//  Vt[128][72] @17408, Pt[128][72] @26624,
//  Ms: ushort[2][512] @35840 (double-buffered dropout half-words)
#define SMEM_SHORTS 36864

__global__ __launch_bounds__(THREADS, 4) void pm_attn(
    const float* __restrict__ Qg, const float* __restrict__ Kg,
    const float* __restrict__ Vg, const float* __restrict__ isf,
    float* __restrict__ Og)
{
  __shared__ __align__(16) short smem[SMEM_SHORTS];
  short* const Khi = smem;
  short* const Klo = smem + 8704;
  short* const Vt  = smem + 17408;
  short* const Pt  = smem + 26624;
  unsigned short* const Ms = (unsigned short*)(smem + 35840);

  const int tid  = threadIdx.x;
  const int lane = tid & 63;
  const int wid  = tid >> 6;       // wave 0..7, owns q rows [wid*16, wid*16+16)
  const int lg   = lane >> 4;      // 0..3
  const int tx   = lane & 15;

  // XCD-aware swizzle: 16 heads per XCD, all 8 q-blocks of a head colocated
  const int swz   = (blockIdx.x & 7) * 128 + (blockIdx.x >> 3);
  const int head  = swz >> 3;
  const int qbase = (swz & 7) * TQ;

  const size_t hoff = (size_t)head * (SS * DD);
  const float* Qh = Qg + hoff + (size_t)qbase * DD;
  const float* Kh = Kg + hoff;
  const float* Vh = Vg + hoff;
  float*       Oh = Og + hoff + (size_t)qbase * DD;

  // ---- Q fragments straight from global (row = wid*16+tx, no LDS) ----
  const int qrow = wid * 16 + tx;
  bf16x8 qhi[4], qlo[4];
#pragma unroll
  for (int ds = 0; ds < 4; ++ds) {
    const float* qp = Qh + qrow * DD + ds * 32 + lg * 8;
    float x[8];
    *(float4*)&x[0] = *(const float4*)qp;
    *(float4*)&x[4] = *(const float4*)(qp + 4);
#pragma unroll
    for (int e = 0; e < 8; ++e) {
      short h, l;
      split2(x[e], h, l);
      qhi[ds][e] = h;
      qlo[ds][e] = l;
    }
  }

  f32x4 acc[8];
#pragma unroll
  for (int n = 0; n < 8; ++n) acc[n] = (f32x4){0.f, 0.f, 0.f, 0.f};
  float mrun = -1e30f, lrun = 0.f;

  // ---- dropout half-word ownership: thread t -> row t>>2, k-base (t&3)*16 ----
  const uint32_t ctrbase = ((uint32_t)head << 20) |
                           ((uint32_t)(qbase + (tid >> 2)) << 10) |
                           (uint32_t)((tid & 3) * 16);
  // prologue: tiles 0 and 1
  Ms[tid]       = (unsigned short)maskhalf(ctrbase);
  Ms[512 + tid] = (unsigned short)maskhalf(ctrbase + 64u);

  const int vd = tid & 127;        // V-stage: this thread's d row
  const int vq = tid >> 7;         // and 16-k quarter

  for (int kt = 0; kt < NKT; ++kt) {
    const float* Kt  = Kh + (size_t)kt * (TK * DD);
    const float* Vtg = Vh + (size_t)kt * (TK * DD);

    __syncthreads();   // (a): prev PV done reading LDS

    // ---- stage K tile: fp32 * (log2e/isf[k]) -> hi/lo bf16 ----
#pragma unroll
    for (int i = 0; i < 4; ++i) {
      int f = tid * 4 + i * 2048;
      int row = f >> 7, col = f & 127;
      float rsk = LOG2E * __builtin_amdgcn_rcpf(isf[kt * 64 + row]);
      float4 k4 = *(const float4*)(Kt + f);
      short h0, h1, h2, h3, l0, l1, l2, l3;
      split2(k4.x * rsk, h0, l0); split2(k4.y * rsk, h1, l1);
      split2(k4.z * rsk, h2, l2); split2(k4.w * rsk, h3, l3);
      uint2 ph = { pack2(h0, h1), pack2(h2, h3) };
      uint2 pl = { pack2(l0, l1), pack2(l2, l3) };
      *(uint2*)&Khi[row * 136 + col] = ph;
      *(uint2*)&Klo[row * 136 + col] = pl;
    }
    // ---- stage V tile transposed: Vt[d][k] = V[k][d], natural k order ----
#pragma unroll
    for (int j4 = 0; j4 < 4; ++j4) {
      int k0 = vq * 16 + j4 * 4;
      float a0 = Vtg[(k0 + 0) * DD + vd];
      float a1 = Vtg[(k0 + 1) * DD + vd];
      float a2 = Vtg[(k0 + 2) * DD + vd];
      float a3 = Vtg[(k0 + 3) * DD + vd];
      uint2 wv = { pack2(f2bf(a0), f2bf(a1)), pack2(f2bf(a2), f2bf(a3)) };
      *(uint2*)&Vt[vd * 72 + k0] = wv;
    }
    __syncthreads();   // (b): K/V visible

    // ---- swapped QK^T: D[k][q] = K·Q^T; lane owns q=tx, k = kj*16+lg*4+r ----
    f32x4 sc[4];
#pragma unroll
    for (int kj = 0; kj < 4; ++kj) sc[kj] = (f32x4){0.f, 0.f, 0.f, 0.f};
#pragma unroll
    for (int ds = 0; ds < 4; ++ds) {
#pragma unroll
      for (int kj = 0; kj < 4; ++kj) {
        int off = (kj * 16 + tx) * 136 + ds * 32 + lg * 8;
        bf16x8 bhi = *(const bf16x8*)&Khi[off];
        bf16x8 blo = *(const bf16x8*)&Klo[off];
        sc[kj] = MFMA16(bhi, qhi[ds], sc[kj]);
        sc[kj] = MFMA16(bhi, qlo[ds], sc[kj]);
        sc[kj] = MFMA16(blo, qhi[ds], sc[kj]);
      }
    }

    // ---- online softmax (log2 domain), defer-max ----
    float pmax = sc[0][0];
#pragma unroll
    for (int kj = 0; kj < 4; ++kj)
#pragma unroll
      for (int r = 0; r < 4; ++r) pmax = fmaxf(pmax, sc[kj][r]);

    if (!__all(pmax <= mrun + DEFER_THR)) {
      float mt = fmaxf(pmax, __shfl_xor(pmax, 16, 64));
      mt = fmaxf(mt, __shfl_xor(mt, 32, 64));
      float mnew = fmaxf(mrun, mt);
      float corr = exp2f(mrun - mnew);
      lrun *= corr;
#pragma unroll
      for (int r = 0; r < 4; ++r) {
        float cr = __shfl(corr, (lane & 48) | (lg * 4 + r), 64);
#pragma unroll
        for (int n = 0; n < 8; ++n) acc[n][r] *= cr;
      }
      mrun = mnew;
    }

    // mask words for this lane's q row
    uint2 ww = *(const uint2*)&Ms[(kt & 1) * 512 + (wid * 16 + tx) * 4];
    float rsum = 0.f;
#pragma unroll
    for (int kj = 0; kj < 4; ++kj) {
      uint32_t w = (kj < 2) ? ww.x : ww.y;
      int bb = (kj & 1) * 16 + lg * 4;
      float p0 = exp2f(sc[kj][0] - mrun);
      float p1 = exp2f(sc[kj][1] - mrun);
      float p2 = exp2f(sc[kj][2] - mrun);
      float p3 = exp2f(sc[kj][3] - mrun);
      rsum += (p0 + p1) + (p2 + p3);
      short b0 = ((w >> (bb + 0)) & 1u) ? f2bf(p0) : (short)0;
      short b1 = ((w >> (bb + 1)) & 1u) ? f2bf(p1) : (short)0;
      short b2 = ((w >> (bb + 2)) & 1u) ? f2bf(p2) : (short)0;
      short b3 = ((w >> (bb + 3)) & 1u) ? f2bf(p3) : (short)0;
      uint2 pw = { pack2(b0, b1), pack2(b2, b3) };
      *(uint2*)&Pt[(wid * 16 + tx) * 72 + kj * 16 + lg * 4] = pw;
    }
    rsum += __shfl_xor(rsum, 16, 64);
    rsum += __shfl_xor(rsum, 32, 64);
    lrun += rsum;

    // ---- pipelined threefry for tile kt+2 (overlaps with PV/MFMA) ----
    uint32_t nexth = 0;
    if (kt + 2 < NKT) nexth = maskhalf(ctrbase + (uint32_t)((kt + 2) * 64));

    __syncthreads();   // (c): P ready; Ms[kt&1] readers done

    if (kt + 2 < NKT) Ms[(kt & 1) * 512 + tid] = (unsigned short)nexth;

    // ---- PV: acc[q][d] += P[q][k] * V[k][d] ----
#pragma unroll
    for (int ks = 0; ks < 2; ++ks) {
      bf16x8 pa = *(const bf16x8*)&Pt[(wid * 16 + tx) * 72 + ks * 32 + lg * 8];
#pragma unroll
      for (int n = 0; n < 8; ++n) {
        bf16x8 vb = *(const bf16x8*)&Vt[(n * 16 + tx) * 72 + ks * 32 + lg * 8];
        acc[n] = MFMA16(pa, vb, acc[n]);
      }
    }
  }

  // ---- epilogue: out = acc / (0.9 * l) ----
#pragma unroll
  for (int r = 0; r < 4; ++r) {
    float lr = __shfl(lrun, (lane & 48) | (lg * 4 + r), 64);
    float inv = 1.0f / (0.9f * lr);
    int orow = wid * 16 + lg * 4 + r;
#pragma unroll
    for (int n = 0; n < 8; ++n)
      Oh[orow * DD + n * 16 + tx] = acc[n][r] * inv;
  }
}

extern "C" void kernel_launch(void* const* d_in, const int* in_sizes, int n_in,
                              void* d_out, int out_size, void* d_ws, size_t ws_size,
                              hipStream_t stream) {
  const float* q   = (const float*)d_in[0];
  const float* k   = (const float*)d_in[1];
  const float* v   = (const float*)d_in[2];
  const float* isf = (const float*)d_in[3];

  pm_attn<<<dim3(NHEAD * (SS / TQ)), dim3(THREADS), 0, stream>>>(
      q, k, v, isf, (float*)d_out);
}